// Round 6
// baseline (390.710 us; speedup 1.0000x reference)
//
#include <hip/hip_runtime.h>
#include <hip/hip_bf16.h>

// B=4, C=256, N=HW=4096, Dqk=32.
// Round 6: attn was LDS-throughput-bound (R5: every wave read the whole 8KB P tile/iter;
// 128KB/iter/CU at 128B/cyc + 512 conflict cyc ~ 45% of iter time, A-frag reuse = 1 MFMA).
//  - attn PV decomposition: wave = (qt = wid&3 q-tile, cg = wid>>2 64-channel group).
//    A-frag (own q-tile) loaded 2x/iter, reused over 4 channel MFMAs -> LDS /4.
//    V frags now read by 4 waves each (identical addresses, barrier-aligned) -> L1 serves dups.
//  - qkv: 512 blocks x 512 thr (2 blocks/CU overlap HBM staging latency), 4-deep load batch.
// Carried: no-max softmax (exp2, LOG2E folded in Wq), LDS-only barrier (vmcnt survives),
// distance-1/2 K/V register prefetch, XCD batch swizzle, packed-W A-frags.

#define N_PIX 4096
#define DQK   32
#define CCH   256
#define LOG2E 1.44269504088896f

typedef __attribute__((ext_vector_type(8))) _Float16 f16x8;
typedef __attribute__((ext_vector_type(4))) _Float16 f16x4;
typedef __attribute__((ext_vector_type(2))) _Float16 f16x2;
typedef __attribute__((ext_vector_type(8))) short    bf16x8;
typedef __attribute__((ext_vector_type(4))) float    f32x4;

// LDS-only block barrier: waits lgkmcnt(0) but leaves vmcnt untouched, so global
// prefetches survive the barrier. 0xc07f = vmcnt 63, expcnt 7, lgkmcnt 0.
__device__ inline void barrier_lds() {
    asm volatile("" ::: "memory");
    __builtin_amdgcn_s_waitcnt(0xc07f);
    __builtin_amdgcn_s_barrier();
    asm volatile("" ::: "memory");
}

// ---------------------------------------------------------------------------
// Kernel 0: pack Wq|Wk|Wv -> f16 A-fragments, lane-ordered (LOG2E folded into Wq).
// Wp[((mt*8+ks)*64 + lane)*8 + j] = W[mt*16 + (lane&15)][ks*32 + (lane>>4)*8 + j]
// ---------------------------------------------------------------------------
__global__ __launch_bounds__(256) void wpack_kernel(
    const float* __restrict__ Wq, const float* __restrict__ Wk,
    const float* __restrict__ Wv, _Float16* __restrict__ Wp)
{
    const int tid   = threadIdx.x;
    const int wflat = blockIdx.x * 4 + (tid >> 6);   // 0..159
    const int lane  = tid & 63;
    const int L15   = lane & 15;
    const int quad  = lane >> 4;
    const int mt    = wflat >> 3;
    const int ks    = wflat & 7;
    const int m0    = mt * 16;

    const float* Wsrc; int row; float scale = 1.f;
    if (m0 < 32)      { Wsrc = Wq; row = m0 + L15;      scale = LOG2E; }
    else if (m0 < 64) { Wsrc = Wk; row = m0 - 32 + L15; }
    else              { Wsrc = Wv; row = m0 - 64 + L15; }

    const float* p = Wsrc + (size_t)row * 256 + ks * 32 + quad * 8;
    f16x8 h;
    #pragma unroll
    for (int j = 0; j < 8; ++j) h[j] = (_Float16)(p[j] * scale);
    *(f16x8*)(Wp + ((size_t)wflat * 64 + lane) * 8) = h;
}

// ---------------------------------------------------------------------------
// Kernel 1: QKV projection, f16 MFMA, packed W.
// Grid 512 (XCD-swizzled), 512 threads = 8 waves, 32-pixel tiles, 2 blocks/CU.
// Wave w: nf = w&1 (16-pixel half), m-tiles (w>>1)*5 .. +4.
// ---------------------------------------------------------------------------
__global__ __launch_bounds__(512, 4) void qkv_kernel(
    const float* __restrict__ x, const _Float16* __restrict__ Wp,
    const float* __restrict__ bq, const float* __restrict__ bk,
    const float* __restrict__ bv,
    _Float16* __restrict__ qo, _Float16* __restrict__ ko,
    __hip_bfloat16* __restrict__ vo)
{
    __shared__ alignas(16) _Float16 xT[32][264];   // [pix][ch], row 528B (16.9 KB)
    const int idx = blockIdx.x;
    const int b   = (idx & 7) >> 1;                       // batch -> XCD pair
    const int n0  = (((idx >> 3) << 1) | (idx & 1)) * 32; // pixel tile
    const int tid = threadIdx.x;

    // stage x[256c][32n] -> xT[n][c] f16; batch all 4 global loads before LDS writes
    {
        const float* xb = x + (size_t)b * CCH * N_PIX;
        float4 ld[2][2];
        int c2s[2], n4s[2];
        #pragma unroll
        for (int pass = 0; pass < 2; ++pass) {
            const int flat = pass * 512 + tid;       // 0..1023
            c2s[pass] = (flat >> 3) * 2;             // even channel 0..254
            n4s[pass] = (flat & 7) * 4;              // 0..28
            ld[pass][0] = *(const float4*)(xb + (size_t)c2s[pass]       * N_PIX + n0 + n4s[pass]);
            ld[pass][1] = *(const float4*)(xb + (size_t)(c2s[pass] + 1) * N_PIX + n0 + n4s[pass]);
        }
        #pragma unroll
        for (int pass = 0; pass < 2; ++pass) {
            const float a[4] = {ld[pass][0].x, ld[pass][0].y, ld[pass][0].z, ld[pass][0].w};
            const float c[4] = {ld[pass][1].x, ld[pass][1].y, ld[pass][1].z, ld[pass][1].w};
            #pragma unroll
            for (int i = 0; i < 4; ++i)
                *(f16x2*)(&xT[n4s[pass] + i][c2s[pass]]) =
                    (f16x2){(_Float16)a[i], (_Float16)c[i]};
        }
    }
    __syncthreads();

    const int lane = tid & 63;
    const int wid  = tid >> 6;
    const int L15  = lane & 15;
    const int quad = lane >> 4;
    const int nf   = wid & 1;
    const int mtg  = wid >> 1;   // 0..3

    const f32x4 fz = {0.f, 0.f, 0.f, 0.f};
    f32x4 acc[5];
    #pragma unroll
    for (int mt = 0; mt < 5; ++mt) acc[mt] = fz;

    const _Float16* wpw = Wp + ((size_t)(mtg * 5) * 8 * 64 + lane) * 8;

    #pragma unroll
    for (int ks = 0; ks < 8; ++ks) {
        const f16x8 bfr = *(const f16x8*)(&xT[nf * 16 + L15][ks * 32 + quad * 8]);
        #pragma unroll
        for (int mt = 0; mt < 5; ++mt) {
            const f16x8 afr = *(const f16x8*)(wpw + (size_t)(mt * 8 + ks) * 512);
            acc[mt] = __builtin_amdgcn_mfma_f32_16x16x32_f16(afr, bfr, acc[mt], 0, 0, 0);
        }
    }

    // epilogue: C/D row = out-row (quad*4+r), col = pixel (L15)
    const int n = n0 + nf * 16 + L15;
    #pragma unroll
    for (int mt = 0; mt < 5; ++mt) {
        const int m0 = (mtg * 5 + mt) * 16;   // never straddles q/k/v bounds
        const f32x4 a = acc[mt];
        if (m0 < 32) {                        // q: [B][N][32] f16 (LOG2E folded in Wp)
            const int mr = m0 + quad * 4;
            f16x4 h;
            #pragma unroll
            for (int r = 0; r < 4; ++r) h[r] = (_Float16)(a[r] + bq[mr + r] * LOG2E);
            *(f16x4*)(qo + ((size_t)b * N_PIX + n) * DQK + mr) = h;
        } else if (m0 < 64) {                 // k: [B][N][32] f16
            const int mr = m0 - 32 + quad * 4;
            f16x4 h;
            #pragma unroll
            for (int r = 0; r < 4; ++r) h[r] = (_Float16)(a[r] + bk[mr + r]);
            *(f16x4*)(ko + ((size_t)b * N_PIX + n) * DQK + mr) = h;
        } else {                              // v: [B][C][N] bf16 (transposed)
            const int c = m0 - 64 + quad * 4;
            #pragma unroll
            for (int r = 0; r < 4; ++r)
                vo[(size_t)b * CCH * N_PIX + (size_t)(c + r) * N_PIX + n] =
                    __float2bfloat16(a[r] + bv[c + r]);
        }
    }
}

// ---------------------------------------------------------------------------
// Kernel 2: attention. Grid 256 (XCD-swizzled), 1024 threads = 16 waves.
// S duty:  wave -> (qt = wid&3 q-tile, kt = wid>>2 16-key slice): 1 MFMA/iter.
// PV duty: wave -> (qt = wid&3 q-tile, cg = wid>>2 64-channel group): 8 MFMA/iter,
//          2 LDS A-frag reads/iter each reused over 4 channel MFMAs.
// ---------------------------------------------------------------------------
__global__ __launch_bounds__(1024, 4) void attn_kernel(
    const _Float16* __restrict__ qg,        // [B][N][32], q pre-scaled by log2e
    const _Float16* __restrict__ kg,        // [B][N][32]
    const __hip_bfloat16* __restrict__ vg,  // [B][C][N]
    float* __restrict__ out)                // [B][C][N]
{
    __shared__ alignas(16) __hip_bfloat16 Ps[2][64][72];   // P tile dbuf, rows 144B
    __shared__ float lsum[4][4][16];                       // [qt][kt][q]

    const int idx  = blockIdx.x;
    const int b    = (idx & 7) >> 1;
    const int n0   = (((idx >> 3) << 1) | (idx & 1)) * 64;
    const int tid  = threadIdx.x;
    const int wid  = tid >> 6;
    const int lane = tid & 63;
    const int L15  = lane & 15;
    const int quad = lane >> 4;
    const int qt   = wid & 3;    // q-tile (both duties)
    const int kt   = wid >> 2;   // S: 16-key slice; PV: 64-channel group
    const int c0   = kt * 64;

    const f32x4 fz = {0.f, 0.f, 0.f, 0.f};

    const f16x8 aq = *(const f16x8*)(qg + ((size_t)b * N_PIX + n0 + qt * 16 + L15) * DQK + quad * 8);

    f32x4 oacc[4];   // 4 channel fragments (c = c0 + cf*16 + L15)
    #pragma unroll
    for (int cf = 0; cf < 4; ++cf) oacc[cf] = fz;
    float psum[4] = {0.f, 0.f, 0.f, 0.f};

    const _Float16* kptr =
        kg + (size_t)b * N_PIX * DQK + (size_t)(kt * 16 + L15) * DQK + quad * 8;
    const __hip_bfloat16* vptr =
        vg + (size_t)b * CCH * N_PIX + (size_t)(c0 + L15) * N_PIX + quad * 8;

    // ---- prologue: K for tiles 0,1; V for tiles 0,1; S/P for tile 0
    const f16x8 k0f = *(const f16x8*)kptr;
    f16x8 kcur = *(const f16x8*)(kptr + 64 * DQK);
    bf16x8 vcur[2][4], vnext[2][4];
    #pragma unroll
    for (int kk = 0; kk < 2; ++kk)
        #pragma unroll
        for (int cf = 0; cf < 4; ++cf) {
            vcur[kk][cf]  = *(const bf16x8*)(vptr + (size_t)(cf * 16) * N_PIX + kk * 32);
            vnext[kk][cf] = *(const bf16x8*)(vptr + (size_t)(cf * 16) * N_PIX + 64 + kk * 32);
        }
    {
        const f32x4 s = __builtin_amdgcn_mfma_f32_16x16x32_f16(aq, k0f, fz, 0, 0, 0);
        #pragma unroll
        for (int r = 0; r < 4; ++r) {
            const float p = exp2f(s[r]); psum[r] += p;
            Ps[0][qt * 16 + quad * 4 + r][kt * 16 + L15] = __float2bfloat16(p);
        }
    }
    barrier_lds();

    for (int it = 0; it < 64; ++it) {
        const int buf = it & 1;
        const int ld  = (it + 2 < 64) ? it + 2 : 63;   // clamped tail prefetch

        // prefetch K(it+2), V(it+2)
        const f16x8 knew = *(const f16x8*)(kptr + (size_t)ld * 64 * DQK);
        bf16x8 vnew[2][4];
        #pragma unroll
        for (int kk = 0; kk < 2; ++kk)
            #pragma unroll
            for (int cf = 0; cf < 4; ++cf)
                vnew[kk][cf] = *(const bf16x8*)(vptr + (size_t)(cf * 16) * N_PIX + (size_t)ld * 64 + kk * 32);

        // PV: O += P(it) V(it) -- own q-tile, 64 channels; A-frag reused x4
        #pragma unroll
        for (int kk = 0; kk < 2; ++kk) {
            const bf16x8 ap = *(const bf16x8*)(&Ps[buf][qt * 16 + L15][kk * 32 + quad * 8]);
            #pragma unroll
            for (int cf = 0; cf < 4; ++cf)
                oacc[cf] = __builtin_amdgcn_mfma_f32_16x16x32_bf16(ap, vcur[kk][cf], oacc[cf], 0, 0, 0);
        }

        // S/P for tile it+1 (k prefetched last iteration)
        if (it < 63) {
            const f32x4 s = __builtin_amdgcn_mfma_f32_16x16x32_f16(aq, kcur, fz, 0, 0, 0);
            #pragma unroll
            for (int r = 0; r < 4; ++r) {
                const float p = exp2f(s[r]); psum[r] += p;
                Ps[buf ^ 1][qt * 16 + quad * 4 + r][kt * 16 + L15] = __float2bfloat16(p);
            }
        }
        barrier_lds();   // LDS-only: vmcnt prefetches stay in flight

        kcur = knew;
        #pragma unroll
        for (int kk = 0; kk < 2; ++kk)
            #pragma unroll
            for (int cf = 0; cf < 4; ++cf) {
                vcur[kk][cf]  = vnext[kk][cf];
                vnext[kk][cf] = vnew[kk][cf];
            }
    }

    // ---- row-sums: reduce over 16 lanes, combine 4 key-slices via LDS
    #pragma unroll
    for (int r = 0; r < 4; ++r) {
        float s = psum[r];
        s += __shfl_xor(s, 1, 64);
        s += __shfl_xor(s, 2, 64);
        s += __shfl_xor(s, 4, 64);
        s += __shfl_xor(s, 8, 64);
        psum[r] = s;
    }
    if (L15 == 0) {
        #pragma unroll
        for (int r = 0; r < 4; ++r) lsum[qt][kt][quad * 4 + r] = psum[r];
    }
    __syncthreads();

    float inv_l[4];
    #pragma unroll
    for (int r = 0; r < 4; ++r) {
        const int q = quad * 4 + r;
        inv_l[r] = 1.f / (lsum[qt][0][q] + lsum[qt][1][q] + lsum[qt][2][q] + lsum[qt][3][q]);
    }

    float* ob = out + (size_t)b * CCH * N_PIX;
    #pragma unroll
    for (int cf = 0; cf < 4; ++cf) {
        const int c = c0 + cf * 16 + L15;
        f32x4 o;
        #pragma unroll
        for (int r = 0; r < 4; ++r) o[r] = oacc[cf][r] * inv_l[r];
        *(f32x4*)(ob + (size_t)c * N_PIX + n0 + qt * 16 + quad * 4) = o;
    }
}

// ---------------------------------------------------------------------------
extern "C" void kernel_launch(void* const* d_in, const int* in_sizes, int n_in,
                              void* d_out, int out_size, void* d_ws, size_t ws_size,
                              hipStream_t stream) {
    (void)in_sizes; (void)n_in; (void)out_size; (void)ws_size;
    const float* x  = (const float*)d_in[0];
    const float* Wq = (const float*)d_in[1];
    const float* bq = (const float*)d_in[2];
    const float* Wk = (const float*)d_in[3];
    const float* bk = (const float*)d_in[4];
    const float* Wv = (const float*)d_in[5];
    const float* bv = (const float*)d_in[6];

    // workspace: q 1MB | k 1MB | v 8MB | Wp 160KB
    _Float16* qb = (_Float16*)d_ws;
    _Float16* kb = qb + (size_t)4 * N_PIX * DQK;
    __hip_bfloat16* vb = (__hip_bfloat16*)(kb + (size_t)4 * N_PIX * DQK);
    _Float16* wp = (_Float16*)(vb + (size_t)4 * CCH * N_PIX);
    float* outp = (float*)d_out;

    wpack_kernel<<<40, 256, 0, stream>>>(Wq, Wk, Wv, wp);
    qkv_kernel<<<512, 512, 0, stream>>>(x, wp, bq, bk, bv, qb, kb, vb);
    attn_kernel<<<256, 1024, 0, stream>>>(qb, kb, vb, outp);
}

// Round 7
// 222.616 us; speedup vs baseline: 1.7551x; 1.7551x over previous
//
#include <hip/hip_runtime.h>
#include <hip/hip_bf16.h>

// B=4, C=256, N=HW=4096, Dqk=32.
// Round 7: R6 spilled (launch_bounds(1024,4) capped VGPR at 64; V bufs went to scratch,
// WRITE_SIZE +17MB). Revert to R5 skeleton with:
//  - __launch_bounds__(1024, 1): no 64-VGPR cap (predict ~110 VGPR, no scratch).
//  - PV duty = (q-pair x 32ch): A-frag reuse x2 -> LDS reads halved vs R5; V dup x2,
//    V buffer = 8 frags (32 VGPR) distance-2 prefetch.
//  - S computed as S^T = mfma(A=K, B=Q) (same register contents, swapped operands):
//    lane then holds 4 keys x 1 query -> P write is ONE ds_write_b64 (was 4x b16,
//    4-way conflicted), psum is a single in-lane scalar.
// Carried: no-max softmax (exp2, LOG2E in packed Wq), LDS-only barrier (vmcnt survives),
// XCD batch swizzle, packed-W qkv (R6 version unchanged).

#define N_PIX 4096
#define DQK   32
#define CCH   256
#define LOG2E 1.44269504088896f

typedef __attribute__((ext_vector_type(8))) _Float16 f16x8;
typedef __attribute__((ext_vector_type(4))) _Float16 f16x4;
typedef __attribute__((ext_vector_type(2))) _Float16 f16x2;
typedef __attribute__((ext_vector_type(8))) short    bf16x8;
typedef __attribute__((ext_vector_type(4))) short    bf16x4;
typedef __attribute__((ext_vector_type(4))) float    f32x4;

// LDS-only block barrier: waits lgkmcnt(0) but leaves vmcnt untouched, so global
// prefetches survive the barrier. 0xc07f = vmcnt 63, expcnt 7, lgkmcnt 0.
__device__ inline void barrier_lds() {
    asm volatile("" ::: "memory");
    __builtin_amdgcn_s_waitcnt(0xc07f);
    __builtin_amdgcn_s_barrier();
    asm volatile("" ::: "memory");
}

__device__ inline short bf16bits(float f) {
    __hip_bfloat16 h = __float2bfloat16(f);
    return *(short*)&h;
}

// ---------------------------------------------------------------------------
// Kernel 0: pack Wq|Wk|Wv -> f16 A-fragments, lane-ordered (LOG2E folded into Wq).
// ---------------------------------------------------------------------------
__global__ __launch_bounds__(256) void wpack_kernel(
    const float* __restrict__ Wq, const float* __restrict__ Wk,
    const float* __restrict__ Wv, _Float16* __restrict__ Wp)
{
    const int tid   = threadIdx.x;
    const int wflat = blockIdx.x * 4 + (tid >> 6);   // 0..159
    const int lane  = tid & 63;
    const int L15   = lane & 15;
    const int quad  = lane >> 4;
    const int mt    = wflat >> 3;
    const int ks    = wflat & 7;
    const int m0    = mt * 16;

    const float* Wsrc; int row; float scale = 1.f;
    if (m0 < 32)      { Wsrc = Wq; row = m0 + L15;      scale = LOG2E; }
    else if (m0 < 64) { Wsrc = Wk; row = m0 - 32 + L15; }
    else              { Wsrc = Wv; row = m0 - 64 + L15; }

    const float* p = Wsrc + (size_t)row * 256 + ks * 32 + quad * 8;
    f16x8 h;
    #pragma unroll
    for (int j = 0; j < 8; ++j) h[j] = (_Float16)(p[j] * scale);
    *(f16x8*)(Wp + ((size_t)wflat * 64 + lane) * 8) = h;
}

// ---------------------------------------------------------------------------
// Kernel 1: QKV projection, f16 MFMA, packed W (unchanged from R6 -- rest-time flat).
// Grid 512 (XCD-swizzled), 512 threads = 8 waves, 32-pixel tiles.
// ---------------------------------------------------------------------------
__global__ __launch_bounds__(512, 4) void qkv_kernel(
    const float* __restrict__ x, const _Float16* __restrict__ Wp,
    const float* __restrict__ bq, const float* __restrict__ bk,
    const float* __restrict__ bv,
    _Float16* __restrict__ qo, _Float16* __restrict__ ko,
    __hip_bfloat16* __restrict__ vo)
{
    __shared__ alignas(16) _Float16 xT[32][264];
    const int idx = blockIdx.x;
    const int b   = (idx & 7) >> 1;
    const int n0  = (((idx >> 3) << 1) | (idx & 1)) * 32;
    const int tid = threadIdx.x;

    {
        const float* xb = x + (size_t)b * CCH * N_PIX;
        float4 ld[2][2];
        int c2s[2], n4s[2];
        #pragma unroll
        for (int pass = 0; pass < 2; ++pass) {
            const int flat = pass * 512 + tid;
            c2s[pass] = (flat >> 3) * 2;
            n4s[pass] = (flat & 7) * 4;
            ld[pass][0] = *(const float4*)(xb + (size_t)c2s[pass]       * N_PIX + n0 + n4s[pass]);
            ld[pass][1] = *(const float4*)(xb + (size_t)(c2s[pass] + 1) * N_PIX + n0 + n4s[pass]);
        }
        #pragma unroll
        for (int pass = 0; pass < 2; ++pass) {
            const float a[4] = {ld[pass][0].x, ld[pass][0].y, ld[pass][0].z, ld[pass][0].w};
            const float c[4] = {ld[pass][1].x, ld[pass][1].y, ld[pass][1].z, ld[pass][1].w};
            #pragma unroll
            for (int i = 0; i < 4; ++i)
                *(f16x2*)(&xT[n4s[pass] + i][c2s[pass]]) =
                    (f16x2){(_Float16)a[i], (_Float16)c[i]};
        }
    }
    __syncthreads();

    const int lane = tid & 63;
    const int wid  = tid >> 6;
    const int L15  = lane & 15;
    const int quad = lane >> 4;
    const int nf   = wid & 1;
    const int mtg  = wid >> 1;

    const f32x4 fz = {0.f, 0.f, 0.f, 0.f};
    f32x4 acc[5];
    #pragma unroll
    for (int mt = 0; mt < 5; ++mt) acc[mt] = fz;

    const _Float16* wpw = Wp + ((size_t)(mtg * 5) * 8 * 64 + lane) * 8;

    #pragma unroll
    for (int ks = 0; ks < 8; ++ks) {
        const f16x8 bfr = *(const f16x8*)(&xT[nf * 16 + L15][ks * 32 + quad * 8]);
        #pragma unroll
        for (int mt = 0; mt < 5; ++mt) {
            const f16x8 afr = *(const f16x8*)(wpw + (size_t)(mt * 8 + ks) * 512);
            acc[mt] = __builtin_amdgcn_mfma_f32_16x16x32_f16(afr, bfr, acc[mt], 0, 0, 0);
        }
    }

    const int n = n0 + nf * 16 + L15;
    #pragma unroll
    for (int mt = 0; mt < 5; ++mt) {
        const int m0 = (mtg * 5 + mt) * 16;
        const f32x4 a = acc[mt];
        if (m0 < 32) {
            const int mr = m0 + quad * 4;
            f16x4 h;
            #pragma unroll
            for (int r = 0; r < 4; ++r) h[r] = (_Float16)(a[r] + bq[mr + r] * LOG2E);
            *(f16x4*)(qo + ((size_t)b * N_PIX + n) * DQK + mr) = h;
        } else if (m0 < 64) {
            const int mr = m0 - 32 + quad * 4;
            f16x4 h;
            #pragma unroll
            for (int r = 0; r < 4; ++r) h[r] = (_Float16)(a[r] + bk[mr + r]);
            *(f16x4*)(ko + ((size_t)b * N_PIX + n) * DQK + mr) = h;
        } else {
            const int c = m0 - 64 + quad * 4;
            #pragma unroll
            for (int r = 0; r < 4; ++r)
                vo[(size_t)b * CCH * N_PIX + (size_t)(c + r) * N_PIX + n] =
                    __float2bfloat16(a[r] + bv[c + r]);
        }
    }
}

// ---------------------------------------------------------------------------
// Kernel 2: attention. Grid 256 (XCD-swizzled), 1024 threads = 16 waves.
// S duty:  wave -> (qt = wid&3, kt = wid>>2): S^T tile = mfma(A=K, B=Q);
//          lane (quad,L15) holds keys kt*16+quad*4..+3 of query qt*16+L15
//          -> one ds_write_b64 into Ps row (qt*16+L15).
// PV duty: wave -> (qp = wid&1 q-pair, cg = wid>>1 32-ch group): 8 MFMA/iter,
//          4 A-frag LDS reads (reuse x2), 4 V frags (dup x2 across q-pairs).
// ---------------------------------------------------------------------------
__global__ __launch_bounds__(1024, 1) void attn_kernel(
    const _Float16* __restrict__ qg,        // [B][N][32], q pre-scaled by log2e
    const _Float16* __restrict__ kg,        // [B][N][32]
    const __hip_bfloat16* __restrict__ vg,  // [B][C][N]
    float* __restrict__ out)                // [B][C][N]
{
    __shared__ alignas(16) __hip_bfloat16 Ps[2][64][72];   // P dbuf, rows 144B
    __shared__ float lsum[4][4][16];                       // [qt][kt][query]

    const int idx  = blockIdx.x;
    const int b    = (idx & 7) >> 1;
    const int n0   = (((idx >> 3) << 1) | (idx & 1)) * 64;
    const int tid  = threadIdx.x;
    const int wid  = tid >> 6;
    const int lane = tid & 63;
    const int L15  = lane & 15;
    const int quad = lane >> 4;
    const int qt   = wid & 3;    // S duty: q-tile
    const int kt   = wid >> 2;   // S duty: 16-key slice
    const int qp   = wid & 1;    // PV duty: q-pair {2qp, 2qp+1}
    const int cg   = wid >> 1;   // PV duty: 32-channel group
    const int c0   = cg * 32;

    const f32x4 fz = {0.f, 0.f, 0.f, 0.f};

    // Q fragment (q-tile qt): serves as B operand of S^T (same register layout)
    const f16x8 aq = *(const f16x8*)(qg + ((size_t)b * N_PIX + n0 + qt * 16 + L15) * DQK + quad * 8);

    f32x4 oacc[2][2];   // [qq][cf]
    #pragma unroll
    for (int qq = 0; qq < 2; ++qq)
        #pragma unroll
        for (int cf = 0; cf < 2; ++cf) oacc[qq][cf] = fz;
    float psum = 0.f;   // in-lane: sum over this lane's keys for query qt*16+L15

    const _Float16* kptr =
        kg + (size_t)b * N_PIX * DQK + (size_t)(kt * 16 + L15) * DQK + quad * 8;
    const __hip_bfloat16* vptr =
        vg + (size_t)b * CCH * N_PIX + (size_t)(c0 + L15) * N_PIX + quad * 8;

    // ---- prologue: K tiles 0,1; V tiles 0,1; S^T/P for tile 0
    const f16x8 k0f = *(const f16x8*)kptr;
    f16x8 kcur = *(const f16x8*)(kptr + 64 * DQK);
    bf16x8 vcur[2][2], vnext[2][2];   // [kk][cf]
    #pragma unroll
    for (int kk = 0; kk < 2; ++kk)
        #pragma unroll
        for (int cf = 0; cf < 2; ++cf) {
            vcur[kk][cf]  = *(const bf16x8*)(vptr + (size_t)(cf * 16) * N_PIX + kk * 32);
            vnext[kk][cf] = *(const bf16x8*)(vptr + (size_t)(cf * 16) * N_PIX + 64 + kk * 32);
        }
    {
        const f32x4 s = __builtin_amdgcn_mfma_f32_16x16x32_f16(k0f, aq, fz, 0, 0, 0);
        bf16x4 pk;
        #pragma unroll
        for (int r = 0; r < 4; ++r) { const float p = exp2f(s[r]); psum += p; pk[r] = bf16bits(p); }
        *(bf16x4*)(&Ps[0][qt * 16 + L15][kt * 16 + quad * 4]) = pk;
    }
    barrier_lds();

    for (int it = 0; it < 64; ++it) {
        const int buf = it & 1;
        const int ld  = (it + 2 < 64) ? it + 2 : 63;   // clamped tail prefetch

        // distance-2 prefetch K(it+2), V(it+2)
        const f16x8 knew = *(const f16x8*)(kptr + (size_t)ld * 64 * DQK);
        bf16x8 vnew[2][2];
        #pragma unroll
        for (int kk = 0; kk < 2; ++kk)
            #pragma unroll
            for (int cf = 0; cf < 2; ++cf)
                vnew[kk][cf] = *(const bf16x8*)(vptr + (size_t)(cf * 16) * N_PIX + (size_t)ld * 64 + kk * 32);

        // PV: O += P(it) V(it) -- q-pair x 32 channels, A-frag reused x2
        #pragma unroll
        for (int qq = 0; qq < 2; ++qq)
            #pragma unroll
            for (int kk = 0; kk < 2; ++kk) {
                const bf16x8 ap = *(const bf16x8*)(&Ps[buf][(qp * 2 + qq) * 16 + L15][kk * 32 + quad * 8]);
                #pragma unroll
                for (int cf = 0; cf < 2; ++cf)
                    oacc[qq][cf] = __builtin_amdgcn_mfma_f32_16x16x32_bf16(ap, vcur[kk][cf], oacc[qq][cf], 0, 0, 0);
            }

        // S^T/P for tile it+1
        if (it < 63) {
            const f32x4 s = __builtin_amdgcn_mfma_f32_16x16x32_f16(kcur, aq, fz, 0, 0, 0);
            bf16x4 pk;
            #pragma unroll
            for (int r = 0; r < 4; ++r) { const float p = exp2f(s[r]); psum += p; pk[r] = bf16bits(p); }
            *(bf16x4*)(&Ps[buf ^ 1][qt * 16 + L15][kt * 16 + quad * 4]) = pk;
        }
        barrier_lds();   // LDS-only: vmcnt prefetches stay in flight

        kcur = knew;
        #pragma unroll
        for (int kk = 0; kk < 2; ++kk)
            #pragma unroll
            for (int cf = 0; cf < 2; ++cf) {
                vcur[kk][cf]  = vnext[kk][cf];
                vnext[kk][cf] = vnew[kk][cf];
            }
    }

    // ---- row-sums: psum is per-lane (query qt*16+L15, this lane's keys).
    // Reduce over the 4 quads holding the same query, then combine kt slices via LDS.
    psum += __shfl_xor(psum, 16, 64);
    psum += __shfl_xor(psum, 32, 64);
    if (quad == 0) lsum[qt][kt][L15] = psum;
    __syncthreads();

    float* ob = out + (size_t)b * CCH * N_PIX;
    #pragma unroll
    for (int qq = 0; qq < 2; ++qq) {
        const int qtile = qp * 2 + qq;
        float inv_l[4];
        #pragma unroll
        for (int r = 0; r < 4; ++r) {
            const int q = quad * 4 + r;
            inv_l[r] = 1.f / (lsum[qtile][0][q] + lsum[qtile][1][q] +
                              lsum[qtile][2][q] + lsum[qtile][3][q]);
        }
        #pragma unroll
        for (int cf = 0; cf < 2; ++cf) {
            const int c = c0 + cf * 16 + L15;
            f32x4 o;
            #pragma unroll
            for (int r = 0; r < 4; ++r) o[r] = oacc[qq][cf][r] * inv_l[r];
            *(f32x4*)(ob + (size_t)c * N_PIX + n0 + qtile * 16 + quad * 4) = o;
        }
    }
}

// ---------------------------------------------------------------------------
extern "C" void kernel_launch(void* const* d_in, const int* in_sizes, int n_in,
                              void* d_out, int out_size, void* d_ws, size_t ws_size,
                              hipStream_t stream) {
    (void)in_sizes; (void)n_in; (void)out_size; (void)ws_size;
    const float* x  = (const float*)d_in[0];
    const float* Wq = (const float*)d_in[1];
    const float* bq = (const float*)d_in[2];
    const float* Wk = (const float*)d_in[3];
    const float* bk = (const float*)d_in[4];
    const float* Wv = (const float*)d_in[5];
    const float* bv = (const float*)d_in[6];

    // workspace: q 1MB | k 1MB | v 8MB | Wp 160KB
    _Float16* qb = (_Float16*)d_ws;
    _Float16* kb = qb + (size_t)4 * N_PIX * DQK;
    __hip_bfloat16* vb = (__hip_bfloat16*)(kb + (size_t)4 * N_PIX * DQK);
    _Float16* wp = (_Float16*)(vb + (size_t)4 * CCH * N_PIX);
    float* outp = (float*)d_out;

    wpack_kernel<<<40, 256, 0, stream>>>(Wq, Wk, Wv, wp);
    qkv_kernel<<<512, 512, 0, stream>>>(x, wp, bq, bk, bv, qb, kb, vb);
    attn_kernel<<<256, 1024, 0, stream>>>(qb, kb, vb, outp);
}

// Round 8
// 147.421 us; speedup vs baseline: 2.6503x; 1.5101x over previous
//
#include <hip/hip_runtime.h>
#include <hip/hip_bf16.h>

// B=4, C=256, N=HW=4096, Dqk=32.
// Round 8: attn was TCP-segment-bound: V[C][N] B-frag loads span 16 cache lines (lane
// stride 8KB); R5->R7 time scaled exactly with segment count (768->1280/iter). Fix at
// the source: qkv stores V PRE-PACKED in MFMA B-frag order (Vp[b][n0>>5][cg16][lane][8])
// via a 20KB LDS transpose -> every attn V load is a coalesced 1KB read. K was already
// coalesced (64B rows). Carried from R7: S^T trick (1 ds_write_b64 P write, scalar psum),
// PV = q-pair x 32ch, LDS-only barrier, XCD batch swizzle, packed-W qkv, no-max softmax.

#define N_PIX 4096
#define DQK   32
#define CCH   256
#define LOG2E 1.44269504088896f

typedef __attribute__((ext_vector_type(8))) _Float16 f16x8;
typedef __attribute__((ext_vector_type(4))) _Float16 f16x4;
typedef __attribute__((ext_vector_type(2))) _Float16 f16x2;
typedef __attribute__((ext_vector_type(8))) short    bf16x8;
typedef __attribute__((ext_vector_type(4))) short    bf16x4;
typedef __attribute__((ext_vector_type(4))) float    f32x4;

// LDS-only block barrier: waits lgkmcnt(0) but leaves vmcnt untouched.
__device__ inline void barrier_lds() {
    asm volatile("" ::: "memory");
    __builtin_amdgcn_s_waitcnt(0xc07f);   // vmcnt=63, expcnt=7, lgkmcnt=0
    __builtin_amdgcn_s_barrier();
    asm volatile("" ::: "memory");
}

__device__ inline short bf16bits(float f) {
    __hip_bfloat16 h = __float2bfloat16(f);
    return *(short*)&h;
}

// ---------------------------------------------------------------------------
// Kernel 0: pack Wq|Wk|Wv -> f16 A-fragments, lane-ordered (LOG2E folded into Wq).
// ---------------------------------------------------------------------------
__global__ __launch_bounds__(256) void wpack_kernel(
    const float* __restrict__ Wq, const float* __restrict__ Wk,
    const float* __restrict__ Wv, _Float16* __restrict__ Wp)
{
    const int tid   = threadIdx.x;
    const int wflat = blockIdx.x * 4 + (tid >> 6);   // 0..159
    const int lane  = tid & 63;
    const int L15   = lane & 15;
    const int quad  = lane >> 4;
    const int mt    = wflat >> 3;
    const int ks    = wflat & 7;
    const int m0    = mt * 16;

    const float* Wsrc; int row; float scale = 1.f;
    if (m0 < 32)      { Wsrc = Wq; row = m0 + L15;      scale = LOG2E; }
    else if (m0 < 64) { Wsrc = Wk; row = m0 - 32 + L15; }
    else              { Wsrc = Wv; row = m0 - 64 + L15; }

    const float* p = Wsrc + (size_t)row * 256 + ks * 32 + quad * 8;
    f16x8 h;
    #pragma unroll
    for (int j = 0; j < 8; ++j) h[j] = (_Float16)(p[j] * scale);
    *(f16x8*)(Wp + ((size_t)wflat * 64 + lane) * 8) = h;
}

// ---------------------------------------------------------------------------
// Kernel 1: QKV projection, f16 MFMA, packed W. Grid 512, 512 thr = 8 waves,
// 32-pixel tiles. V output goes through LDS transpose -> packed B-frag layout:
//   Vp[b][(n0>>5)*16 + cg16][lane(quad,L15)][j] = v[cg16*16+L15][n0 + quad*8+j]
// ---------------------------------------------------------------------------
__global__ __launch_bounds__(512, 4) void qkv_kernel(
    const float* __restrict__ x, const _Float16* __restrict__ Wp,
    const float* __restrict__ bq, const float* __restrict__ bk,
    const float* __restrict__ bv,
    _Float16* __restrict__ qo, _Float16* __restrict__ ko,
    __hip_bfloat16* __restrict__ vp)
{
    // shared: xT (32x264 f16 = 16.9KB) then reused as vst (256x40 bf16 = 20KB)
    __shared__ alignas(16) unsigned char shraw[256 * 40 * 2];
    _Float16       (*xT)[264] = (_Float16 (*)[264])shraw;
    __hip_bfloat16 (*vst)[40] = (__hip_bfloat16 (*)[40])shraw;

    const int idx = blockIdx.x;
    const int b   = (idx & 7) >> 1;
    const int n0  = (((idx >> 3) << 1) | (idx & 1)) * 32;
    const int tid = threadIdx.x;

    // stage x[256c][32n] -> xT[n][c] f16
    {
        const float* xb = x + (size_t)b * CCH * N_PIX;
        float4 ld[2][2];
        int c2s[2], n4s[2];
        #pragma unroll
        for (int pass = 0; pass < 2; ++pass) {
            const int flat = pass * 512 + tid;
            c2s[pass] = (flat >> 3) * 2;
            n4s[pass] = (flat & 7) * 4;
            ld[pass][0] = *(const float4*)(xb + (size_t)c2s[pass]       * N_PIX + n0 + n4s[pass]);
            ld[pass][1] = *(const float4*)(xb + (size_t)(c2s[pass] + 1) * N_PIX + n0 + n4s[pass]);
        }
        #pragma unroll
        for (int pass = 0; pass < 2; ++pass) {
            const float a[4] = {ld[pass][0].x, ld[pass][0].y, ld[pass][0].z, ld[pass][0].w};
            const float c[4] = {ld[pass][1].x, ld[pass][1].y, ld[pass][1].z, ld[pass][1].w};
            #pragma unroll
            for (int i = 0; i < 4; ++i)
                *(f16x2*)(&xT[n4s[pass] + i][c2s[pass]]) =
                    (f16x2){(_Float16)a[i], (_Float16)c[i]};
        }
    }
    __syncthreads();

    const int lane = tid & 63;
    const int wid  = tid >> 6;
    const int L15  = lane & 15;
    const int quad = lane >> 4;
    const int nf   = wid & 1;
    const int mtg  = wid >> 1;

    const f32x4 fz = {0.f, 0.f, 0.f, 0.f};
    f32x4 acc[5];
    #pragma unroll
    for (int mt = 0; mt < 5; ++mt) acc[mt] = fz;

    const _Float16* wpw = Wp + ((size_t)(mtg * 5) * 8 * 64 + lane) * 8;

    #pragma unroll
    for (int ks = 0; ks < 8; ++ks) {
        const f16x8 bfr = *(const f16x8*)(&xT[nf * 16 + L15][ks * 32 + quad * 8]);
        #pragma unroll
        for (int mt = 0; mt < 5; ++mt) {
            const f16x8 afr = *(const f16x8*)(wpw + (size_t)(mt * 8 + ks) * 512);
            acc[mt] = __builtin_amdgcn_mfma_f32_16x16x32_f16(afr, bfr, acc[mt], 0, 0, 0);
        }
    }

    // q/k epilogue (global, no LDS): C/D row = out-row (quad*4+r), col = pixel (L15)
    const int np = nf * 16 + L15;         // local pixel 0..31
    const int n  = n0 + np;
    #pragma unroll
    for (int mt = 0; mt < 5; ++mt) {
        const int m0 = (mtg * 5 + mt) * 16;
        const f32x4 a = acc[mt];
        if (m0 < 32) {
            const int mr = m0 + quad * 4;
            f16x4 h;
            #pragma unroll
            for (int r = 0; r < 4; ++r) h[r] = (_Float16)(a[r] + bq[mr + r] * LOG2E);
            *(f16x4*)(qo + ((size_t)b * N_PIX + n) * DQK + mr) = h;
        } else if (m0 < 64) {
            const int mr = m0 - 32 + quad * 4;
            f16x4 h;
            #pragma unroll
            for (int r = 0; r < 4; ++r) h[r] = (_Float16)(a[r] + bk[mr + r]);
            *(f16x4*)(ko + ((size_t)b * N_PIX + n) * DQK + mr) = h;
        }
    }

    __syncthreads();   // xT dead; vst aliases it

    // v -> LDS transpose buffer vst[ch][pix] (rows padded to 40 elems, 16B-aligned)
    #pragma unroll
    for (int mt = 0; mt < 5; ++mt) {
        const int m0 = (mtg * 5 + mt) * 16;
        if (m0 >= 64) {
            const int c = m0 - 64 + quad * 4;
            #pragma unroll
            for (int r = 0; r < 4; ++r)
                vst[c + r][np] = __float2bfloat16(acc[mt][r] + bv[c + r]);
        }
    }
    __syncthreads();

    // packed store: slot (cg16, lane'=(qd,l15)) -> one b128 LDS read + one 16B store
    {
        __hip_bfloat16* vpb = vp + (size_t)b * 2048 * 512 + (size_t)((n0 >> 5) * 16) * 512;
        #pragma unroll
        for (int s = 0; s < 2; ++s) {
            const int slot = s * 512 + tid;   // 0..1023
            const int cg16 = slot >> 6;
            const int ln   = slot & 63;
            const int qd   = ln >> 4;
            const int l15  = ln & 15;
            const bf16x8 val = *(const bf16x8*)(&vst[cg16 * 16 + l15][qd * 8]);
            *(bf16x8*)(vpb + ((size_t)cg16 * 64 + ln) * 8) = val;
        }
    }
}

// ---------------------------------------------------------------------------
// Kernel 2: attention. Grid 256 (XCD-swizzled), 1024 threads = 16 waves.
// S duty:  wave (qt=wid&3, kt=wid>>2): S^T = mfma(A=K, B=Q); one ds_write_b64.
// PV duty: wave (qp=wid&1, cg=wid>>1): 8 MFMA/iter, 4 LDS A-frags (reuse x2),
//          4 V B-frags -- now COALESCED 1KB loads from packed Vp.
// ---------------------------------------------------------------------------
__global__ __launch_bounds__(1024, 1) void attn_kernel(
    const _Float16* __restrict__ qg,        // [B][N][32], q pre-scaled by log2e
    const _Float16* __restrict__ kg,        // [B][N][32]
    const __hip_bfloat16* __restrict__ vp,  // packed: [B][2048 chunks][64][8]
    float* __restrict__ out)                // [B][C][N]
{
    __shared__ alignas(16) __hip_bfloat16 Ps[2][64][72];   // P dbuf, rows 144B
    __shared__ float lsum[4][4][16];                       // [qt][kt][query]

    const int idx  = blockIdx.x;
    const int b    = (idx & 7) >> 1;
    const int n0   = (((idx >> 3) << 1) | (idx & 1)) * 64;
    const int tid  = threadIdx.x;
    const int wid  = tid >> 6;
    const int lane = tid & 63;
    const int L15  = lane & 15;
    const int quad = lane >> 4;
    const int qt   = wid & 3;    // S duty: q-tile
    const int kt   = wid >> 2;   // S duty: 16-key slice
    const int qp   = wid & 1;    // PV duty: q-pair {2qp, 2qp+1}
    const int cg   = wid >> 1;   // PV duty: 32-channel group
    const int c0   = cg * 32;

    const f32x4 fz = {0.f, 0.f, 0.f, 0.f};

    const f16x8 aq = *(const f16x8*)(qg + ((size_t)b * N_PIX + n0 + qt * 16 + L15) * DQK + quad * 8);

    f32x4 oacc[2][2];   // [qq][cf]
    #pragma unroll
    for (int qq = 0; qq < 2; ++qq)
        #pragma unroll
        for (int cf = 0; cf < 2; ++cf) oacc[qq][cf] = fz;
    float psum = 0.f;

    const _Float16* kptr =
        kg + (size_t)b * N_PIX * DQK + (size_t)(kt * 16 + L15) * DQK + quad * 8;
    // packed V: chunk index = (it*2+kk)*16 + cg16, cg16 = cg*2+cf
    const __hip_bfloat16* vpb = vp + (size_t)b * 2048 * 512 + (size_t)lane * 8;

    // ---- prologue: K tiles 0,1; V tiles 0,1; S^T/P tile 0
    const f16x8 k0f = *(const f16x8*)kptr;
    f16x8 kcur = *(const f16x8*)(kptr + 64 * DQK);
    bf16x8 vcur[2][2], vnext[2][2];   // [kk][cf]
    #pragma unroll
    for (int kk = 0; kk < 2; ++kk)
        #pragma unroll
        for (int cf = 0; cf < 2; ++cf) {
            vcur[kk][cf]  = *(const bf16x8*)(vpb + (size_t)((kk)*16     + cg * 2 + cf) * 512);
            vnext[kk][cf] = *(const bf16x8*)(vpb + (size_t)((2 + kk)*16 + cg * 2 + cf) * 512);
        }
    {
        const f32x4 s = __builtin_amdgcn_mfma_f32_16x16x32_f16(k0f, aq, fz, 0, 0, 0);
        bf16x4 pk;
        #pragma unroll
        for (int r = 0; r < 4; ++r) { const float p = exp2f(s[r]); psum += p; pk[r] = bf16bits(p); }
        *(bf16x4*)(&Ps[0][qt * 16 + L15][kt * 16 + quad * 4]) = pk;
    }
    barrier_lds();

    for (int it = 0; it < 64; ++it) {
        const int buf = it & 1;
        const int ld  = (it + 2 < 64) ? it + 2 : 63;

        // distance-2 prefetch K(it+2), V(it+2) -- all coalesced now
        const f16x8 knew = *(const f16x8*)(kptr + (size_t)ld * 64 * DQK);
        bf16x8 vnew[2][2];
        #pragma unroll
        for (int kk = 0; kk < 2; ++kk)
            #pragma unroll
            for (int cf = 0; cf < 2; ++cf)
                vnew[kk][cf] = *(const bf16x8*)(vpb + (size_t)((ld * 2 + kk) * 16 + cg * 2 + cf) * 512);

        // PV: O += P(it) V(it)
        #pragma unroll
        for (int qq = 0; qq < 2; ++qq)
            #pragma unroll
            for (int kk = 0; kk < 2; ++kk) {
                const bf16x8 ap = *(const bf16x8*)(&Ps[buf][(qp * 2 + qq) * 16 + L15][kk * 32 + quad * 8]);
                #pragma unroll
                for (int cf = 0; cf < 2; ++cf)
                    oacc[qq][cf] = __builtin_amdgcn_mfma_f32_16x16x32_bf16(ap, vcur[kk][cf], oacc[qq][cf], 0, 0, 0);
            }

        // S^T/P tile it+1
        if (it < 63) {
            const f32x4 s = __builtin_amdgcn_mfma_f32_16x16x32_f16(kcur, aq, fz, 0, 0, 0);
            bf16x4 pk;
            #pragma unroll
            for (int r = 0; r < 4; ++r) { const float p = exp2f(s[r]); psum += p; pk[r] = bf16bits(p); }
            *(bf16x4*)(&Ps[buf ^ 1][qt * 16 + L15][kt * 16 + quad * 4]) = pk;
        }
        barrier_lds();

        kcur = knew;
        #pragma unroll
        for (int kk = 0; kk < 2; ++kk)
            #pragma unroll
            for (int cf = 0; cf < 2; ++cf) {
                vcur[kk][cf]  = vnext[kk][cf];
                vnext[kk][cf] = vnew[kk][cf];
            }
    }

    // row-sums: reduce over quads holding same query, combine kt slices via LDS
    psum += __shfl_xor(psum, 16, 64);
    psum += __shfl_xor(psum, 32, 64);
    if (quad == 0) lsum[qt][kt][L15] = psum;
    __syncthreads();

    float* ob = out + (size_t)b * CCH * N_PIX;
    #pragma unroll
    for (int qq = 0; qq < 2; ++qq) {
        const int qtile = qp * 2 + qq;
        float inv_l[4];
        #pragma unroll
        for (int r = 0; r < 4; ++r) {
            const int q = quad * 4 + r;
            inv_l[r] = 1.f / (lsum[qtile][0][q] + lsum[qtile][1][q] +
                              lsum[qtile][2][q] + lsum[qtile][3][q]);
        }
        #pragma unroll
        for (int cf = 0; cf < 2; ++cf) {
            const int c = c0 + cf * 16 + L15;
            f32x4 o;
            #pragma unroll
            for (int r = 0; r < 4; ++r) o[r] = oacc[qq][cf][r] * inv_l[r];
            *(f32x4*)(ob + (size_t)c * N_PIX + n0 + qtile * 16 + quad * 4) = o;
        }
    }
}

// ---------------------------------------------------------------------------
extern "C" void kernel_launch(void* const* d_in, const int* in_sizes, int n_in,
                              void* d_out, int out_size, void* d_ws, size_t ws_size,
                              hipStream_t stream) {
    (void)in_sizes; (void)n_in; (void)out_size; (void)ws_size;
    const float* x  = (const float*)d_in[0];
    const float* Wq = (const float*)d_in[1];
    const float* bq = (const float*)d_in[2];
    const float* Wk = (const float*)d_in[3];
    const float* bk = (const float*)d_in[4];
    const float* Wv = (const float*)d_in[5];
    const float* bv = (const float*)d_in[6];

    // workspace: q 1MB | k 1MB | Vp 8MB | Wp 160KB
    _Float16* qb = (_Float16*)d_ws;
    _Float16* kb = qb + (size_t)4 * N_PIX * DQK;
    __hip_bfloat16* vpk = (__hip_bfloat16*)(kb + (size_t)4 * N_PIX * DQK);
    _Float16* wp = (_Float16*)(vpk + (size_t)4 * 2048 * 512);
    float* outp = (float*)d_out;

    wpack_kernel<<<40, 256, 0, stream>>>(Wq, Wk, Wv, wp);
    qkv_kernel<<<512, 512, 0, stream>>>(x, wp, bq, bk, bv, qb, kb, vpk);
    attn_kernel<<<256, 1024, 0, stream>>>(qb, kb, vpk, outp);
}